// Round 3
// baseline (1372.876 us; speedup 1.0000x reference)
//
#include <hip/hip_runtime.h>
#include <cstdint>
#include <cstddef>

typedef unsigned short u16;
typedef __attribute__((ext_vector_type(8))) short s16x8;
typedef __attribute__((ext_vector_type(4))) float f32x4;

#define LOG2E 1.4426950408889634f

__device__ __forceinline__ float b2f(u16 x) {
    union { unsigned u; float f; } c; c.u = ((unsigned)x) << 16; return c.f;
}
__device__ __forceinline__ u16 f2b(float f) {
    union { float f; unsigned u; } c; c.f = f;
    unsigned u = c.u;
    return (u16)((u + 0x7fffu + ((u >> 16) & 1u)) >> 16);  // RNE
}

// async global->LDS, 16B per lane. LDS dest must be wave-uniform base + lane*16.
__device__ __forceinline__ void gld16(const u16* g, u16* l) {
    __builtin_amdgcn_global_load_lds(
        (const __attribute__((address_space(1))) void*)g,
        (__attribute__((address_space(3))) void*)l, 16, 0, 0);
}

// fp32 -> bf16 converter (n multiple of 2048)
__global__ __launch_bounds__(256)
void cvtf_k(const float* __restrict__ src, u16* __restrict__ dst, int n)
{
    const int i = (blockIdx.x * 256 + threadIdx.x) * 8;
    if (i >= n) return;
    float4 a = *(const float4*)(src + i);
    float4 b = *(const float4*)(src + i + 4);
    s16x8 o;
    o[0] = (short)f2b(a.x); o[1] = (short)f2b(a.y);
    o[2] = (short)f2b(a.z); o[3] = (short)f2b(a.w);
    o[4] = (short)f2b(b.x); o[5] = (short)f2b(b.y);
    o[6] = (short)f2b(b.z); o[7] = (short)f2b(b.w);
    *(s16x8*)(dst + i) = o;
}

enum { EP_PLAIN = 0, EP_ADDF = 1, EP_SILU = 2, EP_VT = 3 };

// C = A[M,K](bf16) @ W[N,K](bf16)^T, fp32 accumulate. M = grid.y*128.
// EP_PLAIN: C bf16
// EP_ADDF:  C fp32 = acc + auxf (fp32; auxf may alias C)
// EP_SILU:  C bf16 = silu(aux bf16) * acc   (aux may alias C)
// EP_VT:    C bf16 scattered per-head: out[((b*4+kv)*128+d)*2048 + s]
template <int MODE>
__global__ __launch_bounds__(256)
void gemm_bt(const u16* __restrict__ A, const u16* __restrict__ W,
             void* Cv, const void* auxv, int N, int K)
{
    __shared__ u16 sA[128 * 32];
    __shared__ u16 sB[128 * 32];
    const int t = threadIdx.x;
    const int w = t >> 6, ln = t & 63;
    const int wr = w >> 1, wc = w & 1;
    const int lq = ln >> 4, lr = ln & 15;
    const int m0 = blockIdx.y * 128, n0 = blockIdx.x * 128;

    const u16* Ab = A + (size_t)(m0 + (t >> 2)) * K + (t & 3) * 8;
    const u16* Bb = W + (size_t)(n0 + (t >> 2)) * K + (t & 3) * 8;
    u16* sAd = sA + t * 8;
    u16* sBd = sB + t * 8;
    const size_t half = (size_t)64 * K;

    f32x4 acc[4][4] = {};

    for (int k0 = 0; k0 < K; k0 += 32) {
        __syncthreads();
        gld16(Ab + k0, sAd);
        gld16(Ab + half + k0, sAd + 2048);
        gld16(Bb + k0, sBd);
        gld16(Bb + half + k0, sBd + 2048);
        __syncthreads();
        s16x8 af[4], bf[4];
#pragma unroll
        for (int i = 0; i < 4; i++)
            af[i] = *(const s16x8*)&sA[(wr * 64 + i * 16 + lr) * 32 + lq * 8];
#pragma unroll
        for (int j = 0; j < 4; j++)
            bf[j] = *(const s16x8*)&sB[(wc * 64 + j * 16 + lr) * 32 + lq * 8];
#pragma unroll
        for (int i = 0; i < 4; i++)
#pragma unroll
            for (int j = 0; j < 4; j++)
                acc[i][j] = __builtin_amdgcn_mfma_f32_16x16x32_bf16(af[i], bf[j], acc[i][j], 0, 0, 0);
    }

#pragma unroll
    for (int i = 0; i < 4; i++) {
#pragma unroll
        for (int j = 0; j < 4; j++) {
#pragma unroll
            for (int r = 0; r < 4; r++) {
                const int m = m0 + wr * 64 + i * 16 + lq * 4 + r;
                const int n = n0 + wc * 64 + j * 16 + lr;
                const float v = acc[i][j][r];
                if (MODE == EP_PLAIN) {
                    ((u16*)Cv)[(size_t)m * N + n] = f2b(v);
                } else if (MODE == EP_ADDF) {
                    float* C = (float*)Cv;
                    const float* aux = (const float*)auxv;
                    C[(size_t)m * N + n] = v + aux[(size_t)m * N + n];
                } else if (MODE == EP_SILU) {
                    const float gv = b2f(((const u16*)auxv)[(size_t)m * N + n]);
                    const float sg = gv / (1.f + __expf(-gv));
                    ((u16*)Cv)[(size_t)m * N + n] = f2b(sg * v);
                } else {  // EP_VT: m -> (b,s), n -> (kv,d); store [b,kv,d,s]
                    const int bb = m >> 11, s = m & 2047;
                    const int kvh = n >> 7, d = n & 127;
                    ((u16*)Cv)[(((size_t)bb * 4 + kvh) * 128 + d) * 2048 + s] = f2b(v);
                }
            }
        }
    }
}

// RMSNorm over rows of 2048, fp32 input, bf16 weight/output.
__global__ __launch_bounds__(256)
void rmsnorm_k(const float* __restrict__ x, const u16* __restrict__ wt, u16* __restrict__ o)
{
    __shared__ float red[4];
    const int row = blockIdx.x, t = threadIdx.x;
    const float* xr = x + (size_t)row * 2048;
    float4 a = *(const float4*)(xr + t * 8);
    float4 b = *(const float4*)(xr + t * 8 + 4);
    float xf[8] = {a.x, a.y, a.z, a.w, b.x, b.y, b.z, b.w};
    float ss = 0.f;
#pragma unroll
    for (int i = 0; i < 8; i++) ss += xf[i] * xf[i];
#pragma unroll
    for (int off = 1; off < 64; off <<= 1) ss += __shfl_xor(ss, off);
    if ((t & 63) == 0) red[t >> 6] = ss;
    __syncthreads();
    const float tot = red[0] + red[1] + red[2] + red[3];
    const float sc = rsqrtf(tot * (1.f / 2048.f) + 1e-5f);
    s16x8 wv = *(const s16x8*)(wt + t * 8);
    s16x8 ov;
#pragma unroll
    for (int i = 0; i < 8; i++) ov[i] = (short)f2b(xf[i] * sc * b2f((u16)wv[i]));
    *(s16x8*)(o + (size_t)row * 2048 + t * 8) = ov;
}

// Flash attention, causal. Q:[B,S,NH*HD] K:[B,S,NKV*HD] VT:[B,NKV,HD,S] -> O:[B,S,NH*HD]
// Block: 128 q-rows, 4 waves x 32 rows. K-tiles of 64 keys.
__global__ __launch_bounds__(256)
void attn_k(const u16* __restrict__ Q, const u16* __restrict__ K,
            const u16* __restrict__ VT, u16* __restrict__ O)
{
    __shared__ u16 kbuf[64 * 128];   // [key][dim]
    __shared__ u16 vtbuf[128 * 64];  // [dim][key]
    __shared__ u16 pbuf[4 * 32 * 64];// per-wave [qrow][key]
    const int qt = blockIdx.x, bh = blockIdx.y;
    const int b = bh >> 4, h = bh & 15, kv = h >> 2;
    const int t = threadIdx.x, w = t >> 6, ln = t & 63;
    const int lq = ln >> 4, lr = ln & 15;
    const u16* qp = Q + (size_t)b * 2048 * 2048 + h * 128;
    const u16* kp = K + (size_t)b * 2048 * 512 + kv * 128;
    const u16* vp = VT + ((size_t)b * 4 + kv) * 128 * 2048;
    const int wrow = qt * 128 + w * 32;

    s16x8 qf[2][4];
#pragma unroll
    for (int i = 0; i < 2; i++)
#pragma unroll
        for (int ks = 0; ks < 4; ks++)
            qf[i][ks] = *(const s16x8*)(qp + (size_t)(wrow + i * 16 + lr) * 2048 + ks * 32 + lq * 8);

    f32x4 oacc[2][8] = {};
    float mi[2][4], li[2][4];
#pragma unroll
    for (int i = 0; i < 2; i++)
#pragma unroll
        for (int r = 0; r < 4; r++) { mi[i][r] = -INFINITY; li[i][r] = 0.f; }

    const int nkt = 2 * qt + 2;
    const u16* kg0 = kp + (size_t)(t >> 4) * 512 + (t & 15) * 8;
    const u16* vg0 = vp + (size_t)(t >> 3) * 2048 + (t & 7) * 8;
    u16* kd = kbuf + t * 8;
    u16* vd = vtbuf + t * 8;
    u16* pw = pbuf + w * 2048;

    for (int kt = 0; kt < nkt; ++kt) {
        __syncthreads();
        const u16* kg = kg0 + (size_t)kt * 64 * 512;
#pragma unroll
        for (int i = 0; i < 4; i++) gld16(kg + (size_t)i * 16 * 512, kd + i * 2048);
        const u16* vg = vg0 + kt * 64;
#pragma unroll
        for (int i = 0; i < 4; i++) gld16(vg + (size_t)i * 32 * 2048, vd + i * 2048);
        __syncthreads();

        f32x4 sacc[2][4] = {};
#pragma unroll
        for (int ks = 0; ks < 4; ks++) {
            s16x8 kf[4];
#pragma unroll
            for (int j = 0; j < 4; j++)
                kf[j] = *(const s16x8*)&kbuf[(j * 16 + lr) * 128 + ks * 32 + lq * 8];
#pragma unroll
            for (int i = 0; i < 2; i++)
#pragma unroll
                for (int j = 0; j < 4; j++)
                    sacc[i][j] = __builtin_amdgcn_mfma_f32_16x16x32_bf16(qf[i][ks], kf[j], sacc[i][j], 0, 0, 0);
        }

        const float scale = 0.08838834764831845f;  // 1/sqrt(128)
        const bool domask = (kt >= 2 * qt);
#pragma unroll
        for (int i = 0; i < 2; i++)
#pragma unroll
            for (int j = 0; j < 4; j++)
#pragma unroll
                for (int r = 0; r < 4; r++) {
                    float s = sacc[i][j][r] * scale;
                    if (domask) {
                        const int key = kt * 64 + j * 16 + lr;
                        const int row = wrow + i * 16 + lq * 4 + r;
                        if (key > row) s = -1e30f;
                    }
                    sacc[i][j][r] = s;
                }
        float alpha[2][4];
#pragma unroll
        for (int i = 0; i < 2; i++)
#pragma unroll
            for (int r = 0; r < 4; r++) {
                float tm = fmaxf(fmaxf(sacc[i][0][r], sacc[i][1][r]),
                                 fmaxf(sacc[i][2][r], sacc[i][3][r]));
#pragma unroll
                for (int off = 1; off < 16; off <<= 1) tm = fmaxf(tm, __shfl_xor(tm, off));
                const float mn = fmaxf(mi[i][r], tm);
                alpha[i][r] = exp2f((mi[i][r] - mn) * LOG2E);
                mi[i][r] = mn;
            }
#pragma unroll
        for (int i = 0; i < 2; i++)
#pragma unroll
            for (int r = 0; r < 4; r++) {
                float rs = 0.f;
#pragma unroll
                for (int j = 0; j < 4; j++) {
                    const float p = exp2f((sacc[i][j][r] - mi[i][r]) * LOG2E);
                    rs += p;
                    pw[(i * 16 + lq * 4 + r) * 64 + j * 16 + lr] = f2b(p);
                }
#pragma unroll
                for (int off = 1; off < 16; off <<= 1) rs += __shfl_xor(rs, off);
                li[i][r] = li[i][r] * alpha[i][r] + rs;
            }
#pragma unroll
        for (int i = 0; i < 2; i++)
#pragma unroll
            for (int jo = 0; jo < 8; jo++)
#pragma unroll
                for (int r = 0; r < 4; r++) oacc[i][jo][r] *= alpha[i][r];
        __syncthreads();  // pbuf writes drained before A-frag reads
#pragma unroll
        for (int ks2 = 0; ks2 < 2; ks2++) {
            s16x8 pf[2];
#pragma unroll
            for (int i = 0; i < 2; i++)
                pf[i] = *(const s16x8*)&pw[(i * 16 + lr) * 64 + ks2 * 32 + lq * 8];
#pragma unroll
            for (int jo = 0; jo < 8; jo++) {
                s16x8 vf = *(const s16x8*)&vtbuf[(jo * 16 + lr) * 64 + ks2 * 32 + lq * 8];
#pragma unroll
                for (int i = 0; i < 2; i++)
                    oacc[i][jo] = __builtin_amdgcn_mfma_f32_16x16x32_bf16(pf[i], vf, oacc[i][jo], 0, 0, 0);
            }
        }
    }

#pragma unroll
    for (int i = 0; i < 2; i++)
#pragma unroll
        for (int jo = 0; jo < 8; jo++)
#pragma unroll
            for (int r = 0; r < 4; r++) {
                const int row = wrow + i * 16 + lq * 4 + r;
                const int d = jo * 16 + lr;
                const float v = oacc[i][jo][r] / li[i][r];
                O[((size_t)b * 2048 + row) * 2048 + h * 128 + d] = f2b(v);
            }
}

extern "C" void kernel_launch(void* const* d_in, const int* in_sizes, int n_in,
                              void* d_out, int out_size, void* d_ws, size_t ws_size,
                              hipStream_t stream)
{
    (void)in_sizes; (void)n_in; (void)out_size; (void)ws_size;
    const float* x = (const float*)d_in[0];   // fp32 inputs (established round 1->2)
    float* out = (float*)d_out;               // fp32 output
    u16* ws = (u16*)d_ws;

    // ---- workspace layout (u16 elements) ----
    u16* wqb = ws;                  //  4,194,304
    u16* wkb = ws + 4194304;        //  1,048,576
    u16* wvb = ws + 5242880;        //  1,048,576
    u16* wob = ws + 6291456;        //  4,194,304
    u16* n1b = ws + 10485760;       //      2,048
    u16* n2b = ws + 10487808;       //      2,048
    u16* wgb = ws + 10489856;       // 16,777,216
    u16* wub = ws + 27267072;       // 16,777,216
    u16* wdb = ws + 44044288;       // 16,777,216
    u16* h1  = ws + 60821504;       //  8,388,608  norm1 out, later attn out
    u16* q   = ws + 69210112;       //  8,388,608  Q, later norm2 out
    u16* kk  = ws + 77598720;       //  2,097,152  K  [B,S,512]
    u16* vT  = ws + 79695872;       //  2,097,152  V^T [B,NKV,HD,S]
    u16* g   = ws + 81793024;       // 33,554,432  gate, then silu(g)*up
    // total 115,347,456 u16 = 230.7 MB

    // ---- weights fp32 -> bf16 ----
    cvtf_k<<<4194304 / 2048, 256, 0, stream>>>((const float*)d_in[2],  wqb, 4194304);
    cvtf_k<<<1048576 / 2048, 256, 0, stream>>>((const float*)d_in[3],  wkb, 1048576);
    cvtf_k<<<1048576 / 2048, 256, 0, stream>>>((const float*)d_in[4],  wvb, 1048576);
    cvtf_k<<<4194304 / 2048, 256, 0, stream>>>((const float*)d_in[5],  wob, 4194304);
    cvtf_k<<<1,              256, 0, stream>>>((const float*)d_in[6],  n1b, 2048);
    cvtf_k<<<1,              256, 0, stream>>>((const float*)d_in[7],  n2b, 2048);
    cvtf_k<<<16777216 / 2048, 256, 0, stream>>>((const float*)d_in[8],  wgb, 16777216);
    cvtf_k<<<16777216 / 2048, 256, 0, stream>>>((const float*)d_in[9],  wub, 16777216);
    cvtf_k<<<16777216 / 2048, 256, 0, stream>>>((const float*)d_in[10], wdb, 16777216);
    // d_in[1] = attention_mask: causal, implemented analytically.

    // ---- transformer block (residual stream in fp32) ----
    rmsnorm_k<<<4096, 256, 0, stream>>>(x, n1b, h1);
    gemm_bt<EP_PLAIN><<<dim3(16, 32), 256, 0, stream>>>(h1, wqb, q, nullptr, 2048, 2048);
    gemm_bt<EP_PLAIN><<<dim3(4, 32), 256, 0, stream>>>(h1, wkb, kk, nullptr, 512, 2048);
    gemm_bt<EP_VT><<<dim3(4, 32), 256, 0, stream>>>(h1, wvb, vT, nullptr, 512, 2048);
    attn_k<<<dim3(16, 32), 256, 0, stream>>>(q, kk, vT, h1);
    gemm_bt<EP_ADDF><<<dim3(16, 32), 256, 0, stream>>>(h1, wob, out, x, 2048, 2048);   // r1 = x + attn@wo^T (fp32)
    rmsnorm_k<<<4096, 256, 0, stream>>>(out, n2b, q);
    gemm_bt<EP_PLAIN><<<dim3(64, 32), 256, 0, stream>>>(q, wgb, g, nullptr, 8192, 2048);
    gemm_bt<EP_SILU><<<dim3(64, 32), 256, 0, stream>>>(q, wub, g, g, 8192, 2048);      // g = silu(g)*up
    gemm_bt<EP_ADDF><<<dim3(16, 32), 256, 0, stream>>>(g, wdb, out, out, 2048, 8192);  // out = r1 + g@wd^T (fp32)
}

// Round 4
// 1223.741 us; speedup vs baseline: 1.1219x; 1.1219x over previous
//
#include <hip/hip_runtime.h>
#include <cstdint>
#include <cstddef>

typedef unsigned short u16;
typedef __attribute__((ext_vector_type(8))) short s16x8;
typedef __attribute__((ext_vector_type(4))) float f32x4;

#define LOG2E 1.4426950408889634f

__device__ __forceinline__ float b2f(u16 x) {
    union { unsigned u; float f; } c; c.u = ((unsigned)x) << 16; return c.f;
}
__device__ __forceinline__ u16 f2b(float f) {
    union { float f; unsigned u; } c; c.f = f;
    unsigned u = c.u;
    return (u16)((u + 0x7fffu + ((u >> 16) & 1u)) >> 16);  // RNE
}

__device__ __forceinline__ void gld16(const u16* g, u16* l) {
    __builtin_amdgcn_global_load_lds(
        (const __attribute__((address_space(1))) void*)g,
        (__attribute__((address_space(3))) void*)l, 16, 0, 0);
}

// XCD-banded tile remap: XCD j (= linear%8, round-robin heuristic) keeps one
// A(m)-tile resident in its L2 while all XCDs stream the same B(n)-tile (LLC
// multicast). gridDim.y must be a multiple of 8.
__device__ __forceinline__ void tile_remap(int& mt, int& nt) {
    const int gx = gridDim.x;
    const int lin = blockIdx.x + blockIdx.y * gx;
    const int per = gx * 8;
    const int grp = lin / per, rem = lin % per;
    mt = grp * 8 + (rem & 7);
    nt = rem >> 3;
}

// fp32 -> bf16 converter (n multiple of 2048)
__global__ __launch_bounds__(256)
void cvtf_k(const float* __restrict__ src, u16* __restrict__ dst, int n)
{
    const int i = (blockIdx.x * 256 + threadIdx.x) * 8;
    if (i >= n) return;
    float4 a = *(const float4*)(src + i);
    float4 b = *(const float4*)(src + i + 4);
    s16x8 o;
    o[0] = (short)f2b(a.x); o[1] = (short)f2b(a.y);
    o[2] = (short)f2b(a.z); o[3] = (short)f2b(a.w);
    o[4] = (short)f2b(b.x); o[5] = (short)f2b(b.y);
    o[6] = (short)f2b(b.z); o[7] = (short)f2b(b.w);
    *(s16x8*)(dst + i) = o;
}

// ---------------------------------------------------------------------------
// GEMM C = A[M,K] @ W[N,K]^T, fp32 accumulate, fused fp32-residual epilogue:
// C(fp32) = acc + aux(fp32). LDS k-chunk XOR swizzle: physical chunk pc holds
// logical kc = pc ^ ((row>>1)&3); staging permutes the global source chunk.
// ---------------------------------------------------------------------------
__global__ __launch_bounds__(256)
void gemm_addf(const u16* __restrict__ A, const u16* __restrict__ W,
               float* __restrict__ C, const float* __restrict__ aux, int N, int K)
{
    __shared__ u16 sA[128 * 32];
    __shared__ u16 sB[128 * 32];
    const int t = threadIdx.x;
    const int w = t >> 6, ln = t & 63;
    const int wr = w >> 1, wc = w & 1;
    const int lq = ln >> 4, lr = ln & 15;
    int mt, nt; tile_remap(mt, nt);
    const int m0 = mt * 128, n0 = nt * 128;

    const int kcs = ((t & 3) ^ ((t >> 3) & 3)) * 8;   // swizzled source chunk
    const u16* Ab = A + (size_t)(m0 + (t >> 2)) * K + kcs;
    const u16* Bb = W + (size_t)(n0 + (t >> 2)) * K + kcs;
    u16* sAd = sA + t * 8;
    u16* sBd = sB + t * 8;
    const size_t half = (size_t)64 * K;
    const int sw = (lr >> 1) & 3;                      // read-side un-swizzle

    f32x4 acc[4][4] = {};

    for (int k0 = 0; k0 < K; k0 += 32) {
        __syncthreads();
        gld16(Ab + k0, sAd);
        gld16(Ab + half + k0, sAd + 2048);
        gld16(Bb + k0, sBd);
        gld16(Bb + half + k0, sBd + 2048);
        __syncthreads();
        s16x8 af[4], bf[4];
#pragma unroll
        for (int i = 0; i < 4; i++)
            af[i] = *(const s16x8*)&sA[(wr * 64 + i * 16 + lr) * 32 + (lq ^ sw) * 8];
#pragma unroll
        for (int j = 0; j < 4; j++)
            bf[j] = *(const s16x8*)&sB[(wc * 64 + j * 16 + lr) * 32 + (lq ^ sw) * 8];
#pragma unroll
        for (int i = 0; i < 4; i++)
#pragma unroll
            for (int j = 0; j < 4; j++)
                acc[i][j] = __builtin_amdgcn_mfma_f32_16x16x32_bf16(af[i], bf[j], acc[i][j], 0, 0, 0);
    }

#pragma unroll
    for (int i = 0; i < 4; i++)
#pragma unroll
        for (int j = 0; j < 4; j++)
#pragma unroll
            for (int r = 0; r < 4; r++) {
                const int m = m0 + wr * 64 + i * 16 + lq * 4 + r;
                const int n = n0 + wc * 64 + j * 16 + lr;
                C[(size_t)m * N + n] = acc[i][j][r] + aux[(size_t)m * N + n];
            }
}

// ---------------------------------------------------------------------------
// Fused gate+up: G[M,N] = silu(A@Wg^T) * (A@Wu^T), bf16 out. K=2048, N=8192.
// ---------------------------------------------------------------------------
__global__ __launch_bounds__(256, 2)
void gemm_gu(const u16* __restrict__ A, const u16* __restrict__ Wg,
             const u16* __restrict__ Wu, u16* __restrict__ G, int N, int K)
{
    __shared__ u16 sA[128 * 32];
    __shared__ u16 sG[128 * 32];
    __shared__ u16 sU[128 * 32];
    const int t = threadIdx.x;
    const int w = t >> 6, ln = t & 63;
    const int wr = w >> 1, wc = w & 1;
    const int lq = ln >> 4, lr = ln & 15;
    int mt, nt; tile_remap(mt, nt);
    const int m0 = mt * 128, n0 = nt * 128;

    const int kcs = ((t & 3) ^ ((t >> 3) & 3)) * 8;
    const u16* Ab = A + (size_t)(m0 + (t >> 2)) * K + kcs;
    const u16* Gb = Wg + (size_t)(n0 + (t >> 2)) * K + kcs;
    const u16* Ub = Wu + (size_t)(n0 + (t >> 2)) * K + kcs;
    u16* sAd = sA + t * 8;
    u16* sGd = sG + t * 8;
    u16* sUd = sU + t * 8;
    const size_t half = (size_t)64 * K;
    const int sw = (lr >> 1) & 3;

    f32x4 ag[4][4] = {}, au[4][4] = {};

    for (int k0 = 0; k0 < K; k0 += 32) {
        __syncthreads();
        gld16(Ab + k0, sAd);
        gld16(Ab + half + k0, sAd + 2048);
        gld16(Gb + k0, sGd);
        gld16(Gb + half + k0, sGd + 2048);
        gld16(Ub + k0, sUd);
        gld16(Ub + half + k0, sUd + 2048);
        __syncthreads();
        s16x8 af[4], bg[4], bu[4];
#pragma unroll
        for (int i = 0; i < 4; i++)
            af[i] = *(const s16x8*)&sA[(wr * 64 + i * 16 + lr) * 32 + (lq ^ sw) * 8];
#pragma unroll
        for (int j = 0; j < 4; j++) {
            bg[j] = *(const s16x8*)&sG[(wc * 64 + j * 16 + lr) * 32 + (lq ^ sw) * 8];
            bu[j] = *(const s16x8*)&sU[(wc * 64 + j * 16 + lr) * 32 + (lq ^ sw) * 8];
        }
#pragma unroll
        for (int i = 0; i < 4; i++)
#pragma unroll
            for (int j = 0; j < 4; j++) {
                ag[i][j] = __builtin_amdgcn_mfma_f32_16x16x32_bf16(af[i], bg[j], ag[i][j], 0, 0, 0);
                au[i][j] = __builtin_amdgcn_mfma_f32_16x16x32_bf16(af[i], bu[j], au[i][j], 0, 0, 0);
            }
    }

#pragma unroll
    for (int i = 0; i < 4; i++)
#pragma unroll
        for (int j = 0; j < 4; j++)
#pragma unroll
            for (int r = 0; r < 4; r++) {
                const int m = m0 + wr * 64 + i * 16 + lq * 4 + r;
                const int n = n0 + wc * 64 + j * 16 + lr;
                const float gv = ag[i][j][r];
                const float sg = gv / (1.f + __expf(-gv));
                G[(size_t)m * N + n] = f2b(sg * au[i][j][r]);
            }
}

// ---------------------------------------------------------------------------
// Fused QKV projection. A[M,2048]; n-tiles 0..15 -> Q[M,2048],
// 16..19 -> K[M,512], 20..23 -> V^T scatter [B,NKV,HD,S]. K=2048.
// ---------------------------------------------------------------------------
__global__ __launch_bounds__(256)
void gemm_qkv(const u16* __restrict__ A, const u16* __restrict__ wq,
              const u16* __restrict__ wk, const u16* __restrict__ wv,
              u16* __restrict__ Q, u16* __restrict__ Kk, u16* __restrict__ VT)
{
    __shared__ u16 sA[128 * 32];
    __shared__ u16 sB[128 * 32];
    const int t = threadIdx.x;
    const int w = t >> 6, ln = t & 63;
    const int wr = w >> 1, wc = w & 1;
    const int lq = ln >> 4, lr = ln & 15;
    int mt, nt; tile_remap(mt, nt);
    const int m0 = mt * 128;
    const int K = 2048;

    const u16* Wbase; int nl, route;
    if (nt < 16)      { Wbase = wq; nl = nt * 128;        route = 0; }
    else if (nt < 20) { Wbase = wk; nl = (nt - 16) * 128; route = 1; }
    else              { Wbase = wv; nl = (nt - 20) * 128; route = 2; }

    const int kcs = ((t & 3) ^ ((t >> 3) & 3)) * 8;
    const u16* Ab = A + (size_t)(m0 + (t >> 2)) * K + kcs;
    const u16* Bb = Wbase + (size_t)(nl + (t >> 2)) * K + kcs;
    u16* sAd = sA + t * 8;
    u16* sBd = sB + t * 8;
    const size_t half = (size_t)64 * K;
    const int sw = (lr >> 1) & 3;

    f32x4 acc[4][4] = {};

    for (int k0 = 0; k0 < K; k0 += 32) {
        __syncthreads();
        gld16(Ab + k0, sAd);
        gld16(Ab + half + k0, sAd + 2048);
        gld16(Bb + k0, sBd);
        gld16(Bb + half + k0, sBd + 2048);
        __syncthreads();
        s16x8 af[4], bf[4];
#pragma unroll
        for (int i = 0; i < 4; i++)
            af[i] = *(const s16x8*)&sA[(wr * 64 + i * 16 + lr) * 32 + (lq ^ sw) * 8];
#pragma unroll
        for (int j = 0; j < 4; j++)
            bf[j] = *(const s16x8*)&sB[(wc * 64 + j * 16 + lr) * 32 + (lq ^ sw) * 8];
#pragma unroll
        for (int i = 0; i < 4; i++)
#pragma unroll
            for (int j = 0; j < 4; j++)
                acc[i][j] = __builtin_amdgcn_mfma_f32_16x16x32_bf16(af[i], bf[j], acc[i][j], 0, 0, 0);
    }

#pragma unroll
    for (int i = 0; i < 4; i++)
#pragma unroll
        for (int j = 0; j < 4; j++)
#pragma unroll
            for (int r = 0; r < 4; r++) {
                const int m = m0 + wr * 64 + i * 16 + lq * 4 + r;
                const int nc = nl + wc * 64 + j * 16 + lr;   // col within route
                const u16 v = f2b(acc[i][j][r]);
                if (route == 0) {
                    Q[(size_t)m * 2048 + nc] = v;
                } else if (route == 1) {
                    Kk[(size_t)m * 512 + nc] = v;
                } else {
                    const int bb = m >> 11, s = m & 2047;
                    const int kv = nc >> 7, d = nc & 127;
                    VT[(((size_t)bb * 4 + kv) * 128 + d) * 2048 + s] = v;
                }
            }
}

// RMSNorm over rows of 2048, fp32 input, bf16 weight/output.
__global__ __launch_bounds__(256)
void rmsnorm_k(const float* __restrict__ x, const u16* __restrict__ wt, u16* __restrict__ o)
{
    __shared__ float red[4];
    const int row = blockIdx.x, t = threadIdx.x;
    const float* xr = x + (size_t)row * 2048;
    float4 a = *(const float4*)(xr + t * 8);
    float4 b = *(const float4*)(xr + t * 8 + 4);
    float xf[8] = {a.x, a.y, a.z, a.w, b.x, b.y, b.z, b.w};
    float ss = 0.f;
#pragma unroll
    for (int i = 0; i < 8; i++) ss += xf[i] * xf[i];
#pragma unroll
    for (int off = 1; off < 64; off <<= 1) ss += __shfl_xor(ss, off);
    if ((t & 63) == 0) red[t >> 6] = ss;
    __syncthreads();
    const float tot = red[0] + red[1] + red[2] + red[3];
    const float sc = rsqrtf(tot * (1.f / 2048.f) + 1e-5f);
    s16x8 wv = *(const s16x8*)(wt + t * 8);
    s16x8 ov;
#pragma unroll
    for (int i = 0; i < 8; i++) ov[i] = (short)f2b(xf[i] * sc * b2f((u16)wv[i]));
    *(s16x8*)(o + (size_t)row * 2048 + t * 8) = ov;
}

// ---------------------------------------------------------------------------
// Flash attention, causal. Q:[B,S,2048] K:[B,S,512] VT:[B,NKV,128,S].
// 128 q-rows/block, 4 waves x 32 rows, 64-key tiles. All LDS tiles use
// XOR chunk swizzles to kill the 16-way bank conflicts of the naive layout.
// ---------------------------------------------------------------------------
__global__ __launch_bounds__(256)
void attn_k(const u16* __restrict__ Q, const u16* __restrict__ K,
            const u16* __restrict__ VT, u16* __restrict__ O)
{
    __shared__ u16 kbuf[64 * 128];   // [key][dim], 16-chunk swizzle
    __shared__ u16 vtbuf[128 * 64];  // [dim][key], 8-chunk swizzle
    __shared__ u16 pbuf[4 * 32 * 64];// per-wave [qrow][key], 8-chunk swizzle
    const int qt = blockIdx.x, bh = blockIdx.y;
    const int b = bh >> 4, h = bh & 15, kv = h >> 2;
    const int t = threadIdx.x, w = t >> 6, ln = t & 63;
    const int lq = ln >> 4, lr = ln & 15;
    const u16* qp = Q + (size_t)b * 2048 * 2048 + h * 128;
    const u16* kp = K + (size_t)b * 2048 * 512 + kv * 128;
    const u16* vp = VT + ((size_t)b * 4 + kv) * 128 * 2048;
    const int wrow = qt * 128 + w * 32;

    s16x8 qf[2][4];
#pragma unroll
    for (int i = 0; i < 2; i++)
#pragma unroll
        for (int ks = 0; ks < 4; ks++)
            qf[i][ks] = *(const s16x8*)(qp + (size_t)(wrow + i * 16 + lr) * 2048 + ks * 32 + lq * 8);

    f32x4 oacc[2][8] = {};
    float mi[2][4], li[2][4];
#pragma unroll
    for (int i = 0; i < 2; i++)
#pragma unroll
        for (int r = 0; r < 4; r++) { mi[i][r] = -INFINITY; li[i][r] = 0.f; }

    const int nkt = 2 * qt + 2;
    // swizzled staging source offsets
    const int kswz = (t & 15) ^ ((t >> 4) & 15);
    const int vswz = (t & 7) ^ ((t >> 3) & 7);
    const u16* kg0 = kp + (size_t)(t >> 4) * 512 + kswz * 8;
    const u16* vg0 = vp + (size_t)(t >> 3) * 2048 + vswz * 8;
    u16* kd = kbuf + t * 8;
    u16* vd = vtbuf + t * 8;
    u16* pw = pbuf + w * 2048;
    const int lr7 = lr & 7;

    for (int kt = 0; kt < nkt; ++kt) {
        __syncthreads();
        const u16* kg = kg0 + (size_t)kt * 64 * 512;
#pragma unroll
        for (int i = 0; i < 4; i++) gld16(kg + (size_t)i * 16 * 512, kd + i * 2048);
        const u16* vg = vg0 + kt * 64;
#pragma unroll
        for (int i = 0; i < 4; i++) gld16(vg + (size_t)i * 32 * 2048, vd + i * 2048);
        __syncthreads();

        f32x4 sacc[2][4] = {};
#pragma unroll
        for (int ks = 0; ks < 4; ks++) {
            s16x8 kf[4];
#pragma unroll
            for (int j = 0; j < 4; j++)
                kf[j] = *(const s16x8*)&kbuf[(j * 16 + lr) * 128 + ((ks * 4 + lq) ^ lr) * 8];
#pragma unroll
            for (int i = 0; i < 2; i++)
#pragma unroll
                for (int j = 0; j < 4; j++)
                    sacc[i][j] = __builtin_amdgcn_mfma_f32_16x16x32_bf16(qf[i][ks], kf[j], sacc[i][j], 0, 0, 0);
        }

        const float scale = 0.08838834764831845f;  // 1/sqrt(128)
        const bool domask = (kt >= 2 * qt);
#pragma unroll
        for (int i = 0; i < 2; i++)
#pragma unroll
            for (int j = 0; j < 4; j++)
#pragma unroll
                for (int r = 0; r < 4; r++) {
                    float s = sacc[i][j][r] * scale;
                    if (domask) {
                        const int key = kt * 64 + j * 16 + lr;
                        const int row = wrow + i * 16 + lq * 4 + r;
                        if (key > row) s = -1e30f;
                    }
                    sacc[i][j][r] = s;
                }
        float alpha[2][4];
#pragma unroll
        for (int i = 0; i < 2; i++)
#pragma unroll
            for (int r = 0; r < 4; r++) {
                float tm = fmaxf(fmaxf(sacc[i][0][r], sacc[i][1][r]),
                                 fmaxf(sacc[i][2][r], sacc[i][3][r]));
#pragma unroll
                for (int off = 1; off < 16; off <<= 1) tm = fmaxf(tm, __shfl_xor(tm, off));
                const float mn = fmaxf(mi[i][r], tm);
                alpha[i][r] = exp2f((mi[i][r] - mn) * LOG2E);
                mi[i][r] = mn;
            }
#pragma unroll
        for (int i = 0; i < 2; i++)
#pragma unroll
            for (int r = 0; r < 4; r++) {
                const int qrow = i * 16 + lq * 4 + r;
                float rs = 0.f;
#pragma unroll
                for (int j = 0; j < 4; j++) {
                    const float p = exp2f((sacc[i][j][r] - mi[i][r]) * LOG2E);
                    rs += p;
                    const int key = j * 16 + lr;
                    pw[qrow * 64 + (((key >> 3) ^ (qrow & 7)) << 3) + (key & 7)] = f2b(p);
                }
#pragma unroll
                for (int off = 1; off < 16; off <<= 1) rs += __shfl_xor(rs, off);
                li[i][r] = li[i][r] * alpha[i][r] + rs;
            }
#pragma unroll
        for (int i = 0; i < 2; i++)
#pragma unroll
            for (int jo = 0; jo < 8; jo++)
#pragma unroll
                for (int r = 0; r < 4; r++) oacc[i][jo][r] *= alpha[i][r];
        __syncthreads();  // pbuf writes drained before A-frag reads
#pragma unroll
        for (int ks2 = 0; ks2 < 2; ks2++) {
            s16x8 pf[2];
#pragma unroll
            for (int i = 0; i < 2; i++)
                pf[i] = *(const s16x8*)&pw[(i * 16 + lr) * 64 + ((ks2 * 4 + lq) ^ lr7) * 8];
#pragma unroll
            for (int jo = 0; jo < 8; jo++) {
                s16x8 vf = *(const s16x8*)&vtbuf[(jo * 16 + lr) * 64 + ((ks2 * 4 + lq) ^ lr7) * 8];
#pragma unroll
                for (int i = 0; i < 2; i++)
                    oacc[i][jo] = __builtin_amdgcn_mfma_f32_16x16x32_bf16(pf[i], vf, oacc[i][jo], 0, 0, 0);
            }
        }
    }

#pragma unroll
    for (int i = 0; i < 2; i++)
#pragma unroll
        for (int jo = 0; jo < 8; jo++)
#pragma unroll
            for (int r = 0; r < 4; r++) {
                const int row = wrow + i * 16 + lq * 4 + r;
                const int d = jo * 16 + lr;
                const float v = oacc[i][jo][r] / li[i][r];
                O[((size_t)b * 2048 + row) * 2048 + h * 128 + d] = f2b(v);
            }
}

extern "C" void kernel_launch(void* const* d_in, const int* in_sizes, int n_in,
                              void* d_out, int out_size, void* d_ws, size_t ws_size,
                              hipStream_t stream)
{
    (void)in_sizes; (void)n_in; (void)out_size; (void)ws_size;
    const float* x = (const float*)d_in[0];   // fp32 inputs
    float* out = (float*)d_out;               // fp32 output
    u16* ws = (u16*)d_ws;

    // ---- workspace layout (u16 elements) ----
    u16* wqb = ws;                  //  4,194,304
    u16* wkb = ws + 4194304;        //  1,048,576
    u16* wvb = ws + 5242880;        //  1,048,576
    u16* wob = ws + 6291456;        //  4,194,304
    u16* n1b = ws + 10485760;       //      2,048
    u16* n2b = ws + 10487808;       //      2,048
    u16* wgb = ws + 10489856;       // 16,777,216
    u16* wub = ws + 27267072;       // 16,777,216
    u16* wdb = ws + 44044288;       // 16,777,216
    u16* h1  = ws + 60821504;       //  8,388,608  norm1 out, later attn out
    u16* q   = ws + 69210112;       //  8,388,608  Q, later norm2 out
    u16* kk  = ws + 77598720;       //  2,097,152  K  [B,S,512]
    u16* vT  = ws + 79695872;       //  2,097,152  V^T [B,NKV,HD,S]
    u16* g   = ws + 81793024;       // 33,554,432  silu(gate)*up

    // ---- weights fp32 -> bf16 ----
    cvtf_k<<<4194304 / 2048, 256, 0, stream>>>((const float*)d_in[2],  wqb, 4194304);
    cvtf_k<<<1048576 / 2048, 256, 0, stream>>>((const float*)d_in[3],  wkb, 1048576);
    cvtf_k<<<1048576 / 2048, 256, 0, stream>>>((const float*)d_in[4],  wvb, 1048576);
    cvtf_k<<<4194304 / 2048, 256, 0, stream>>>((const float*)d_in[5],  wob, 4194304);
    cvtf_k<<<1,              256, 0, stream>>>((const float*)d_in[6],  n1b, 2048);
    cvtf_k<<<1,              256, 0, stream>>>((const float*)d_in[7],  n2b, 2048);
    cvtf_k<<<16777216 / 2048, 256, 0, stream>>>((const float*)d_in[8],  wgb, 16777216);
    cvtf_k<<<16777216 / 2048, 256, 0, stream>>>((const float*)d_in[9],  wub, 16777216);
    cvtf_k<<<16777216 / 2048, 256, 0, stream>>>((const float*)d_in[10], wdb, 16777216);
    // d_in[1] = attention_mask: causal, analytic.

    // ---- transformer block (residual stream in fp32) ----
    rmsnorm_k<<<4096, 256, 0, stream>>>(x, n1b, h1);
    gemm_qkv<<<dim3(24, 32), 256, 0, stream>>>(h1, wqb, wkb, wvb, q, kk, vT);
    attn_k<<<dim3(16, 32), 256, 0, stream>>>(q, kk, vT, h1);
    gemm_addf<<<dim3(16, 32), 256, 0, stream>>>(h1, wob, out, x, 2048, 2048);   // r1 = x + attn@wo^T
    rmsnorm_k<<<4096, 256, 0, stream>>>(out, n2b, q);
    gemm_gu<<<dim3(64, 32), 256, 0, stream>>>(q, wgb, wub, g, 8192, 2048);      // g = silu(x@wg^T)*(x@wu^T)
    gemm_addf<<<dim3(16, 32), 256, 0, stream>>>(g, wdb, out, out, 2048, 8192);  // out = r1 + g@wd^T
}

// Round 5
// 1194.072 us; speedup vs baseline: 1.1497x; 1.0248x over previous
//
#include <hip/hip_runtime.h>
#include <cstdint>
#include <cstddef>

typedef unsigned short u16;
typedef __attribute__((ext_vector_type(8))) short s16x8;
typedef __attribute__((ext_vector_type(4))) float f32x4;

#define LOG2E 1.4426950408889634f

__device__ __forceinline__ float b2f(u16 x) {
    union { unsigned u; float f; } c; c.u = ((unsigned)x) << 16; return c.f;
}
__device__ __forceinline__ u16 f2b(float f) {
    union { float f; unsigned u; } c; c.f = f;
    unsigned u = c.u;
    return (u16)((u + 0x7fffu + ((u >> 16) & 1u)) >> 16);  // RNE
}

__device__ __forceinline__ void gld16(const u16* g, u16* l) {
    __builtin_amdgcn_global_load_lds(
        (const __attribute__((address_space(1))) void*)g,
        (__attribute__((address_space(3))) void*)l, 16, 0, 0);
}

// XCD-aware remap, v2. Total blocks = NT*32 (32 m-tiles always).
// XCD j (= lin%8 round-robin heuristic) owns m-tiles {j, j+8, j+16, j+24}
// (2 MB of A, L2-resident all kernel); n swept ONCE, the 4 same-nt blocks of
// an XCD adjacent in launch order so each W-tile is fetched ~once per XCD.
__device__ __forceinline__ void tile_remap(int& mt, int& nt) {
    const int lin = blockIdx.x + blockIdx.y * gridDim.x;
    mt = ((lin >> 3) & 3) * 8 + (lin & 7);
    nt = lin >> 5;
}

// ---------------------------------------------------------------------------
// Merged fp32->bf16 conversion of all weights into one contiguous ws region.
// Segment order: wq wk wv wo wg wu wd n1 n2 (offsets in 2048-elem units).
// ---------------------------------------------------------------------------
__global__ __launch_bounds__(256)
void cvt_all(const float* __restrict__ s0, const float* __restrict__ s1,
             const float* __restrict__ s2, const float* __restrict__ s3,
             const float* __restrict__ s4, const float* __restrict__ s5,
             const float* __restrict__ s6, const float* __restrict__ s7,
             const float* __restrict__ s8, u16* __restrict__ dst)
{
    const size_t base = (size_t)blockIdx.x * 2048;
    const size_t off1 = 4194304, off2 = 5242880, off3 = 6291456,
                 off4 = 10485760, off5 = 27262976, off6 = 44040192,
                 off7 = 60817408, off8 = 60819456;
    const float* s; size_t o;
    if      (base < off1) { s = s0; o = 0; }
    else if (base < off2) { s = s1; o = off1; }
    else if (base < off3) { s = s2; o = off2; }
    else if (base < off4) { s = s3; o = off3; }
    else if (base < off5) { s = s4; o = off4; }
    else if (base < off6) { s = s5; o = off5; }
    else if (base < off7) { s = s6; o = off6; }
    else if (base < off8) { s = s7; o = off7; }
    else                  { s = s8; o = off8; }
    const size_t i = base - o + threadIdx.x * 8;
    float4 a = *(const float4*)(s + i);
    float4 b = *(const float4*)(s + i + 4);
    s16x8 v;
    v[0] = (short)f2b(a.x); v[1] = (short)f2b(a.y);
    v[2] = (short)f2b(a.z); v[3] = (short)f2b(a.w);
    v[4] = (short)f2b(b.x); v[5] = (short)f2b(b.y);
    v[6] = (short)f2b(b.z); v[7] = (short)f2b(b.w);
    *(s16x8*)(dst + base + threadIdx.x * 8) = v;
}

// ---------------------------------------------------------------------------
// GEMM C = A[M,K] @ W[N,K]^T, fp32 accumulate, fused fp32-residual epilogue:
// C(fp32) = acc + aux(fp32). LDS k-chunk XOR swizzle (conflict-free, verified
// round 4: SQ_LDS_BANK_CONFLICT = 0).
// ---------------------------------------------------------------------------
__global__ __launch_bounds__(256)
void gemm_addf(const u16* __restrict__ A, const u16* __restrict__ W,
               float* __restrict__ C, const float* __restrict__ aux, int N, int K)
{
    __shared__ u16 sA[128 * 32];
    __shared__ u16 sB[128 * 32];
    const int t = threadIdx.x;
    const int w = t >> 6, ln = t & 63;
    const int wr = w >> 1, wc = w & 1;
    const int lq = ln >> 4, lr = ln & 15;
    int mt, nt; tile_remap(mt, nt);
    const int m0 = mt * 128, n0 = nt * 128;

    const int kcs = ((t & 3) ^ ((t >> 3) & 3)) * 8;   // swizzled source chunk
    const u16* Ab = A + (size_t)(m0 + (t >> 2)) * K + kcs;
    const u16* Bb = W + (size_t)(n0 + (t >> 2)) * K + kcs;
    u16* sAd = sA + t * 8;
    u16* sBd = sB + t * 8;
    const size_t half = (size_t)64 * K;
    const int sw = (lr >> 1) & 3;                      // read-side un-swizzle

    f32x4 acc[4][4] = {};

    for (int k0 = 0; k0 < K; k0 += 32) {
        __syncthreads();
        gld16(Ab + k0, sAd);
        gld16(Ab + half + k0, sAd + 2048);
        gld16(Bb + k0, sBd);
        gld16(Bb + half + k0, sBd + 2048);
        __syncthreads();
        s16x8 af[4], bf[4];
#pragma unroll
        for (int i = 0; i < 4; i++)
            af[i] = *(const s16x8*)&sA[(wr * 64 + i * 16 + lr) * 32 + (lq ^ sw) * 8];
#pragma unroll
        for (int j = 0; j < 4; j++)
            bf[j] = *(const s16x8*)&sB[(wc * 64 + j * 16 + lr) * 32 + (lq ^ sw) * 8];
#pragma unroll
        for (int i = 0; i < 4; i++)
#pragma unroll
            for (int j = 0; j < 4; j++)
                acc[i][j] = __builtin_amdgcn_mfma_f32_16x16x32_bf16(af[i], bf[j], acc[i][j], 0, 0, 0);
    }

#pragma unroll
    for (int i = 0; i < 4; i++)
#pragma unroll
        for (int j = 0; j < 4; j++)
#pragma unroll
            for (int r = 0; r < 4; r++) {
                const int m = m0 + wr * 64 + i * 16 + lq * 4 + r;
                const int n = n0 + wc * 64 + j * 16 + lr;
                C[(size_t)m * N + n] = acc[i][j][r] + aux[(size_t)m * N + n];
            }
}

// ---------------------------------------------------------------------------
// Fused gate+up: G[M,N] = silu(A@Wg^T) * (A@Wu^T), bf16 out. K=2048, N=8192.
// ---------------------------------------------------------------------------
__global__ __launch_bounds__(256, 2)
void gemm_gu(const u16* __restrict__ A, const u16* __restrict__ Wg,
             const u16* __restrict__ Wu, u16* __restrict__ G, int N, int K)
{
    __shared__ u16 sA[128 * 32];
    __shared__ u16 sG[128 * 32];
    __shared__ u16 sU[128 * 32];
    const int t = threadIdx.x;
    const int w = t >> 6, ln = t & 63;
    const int wr = w >> 1, wc = w & 1;
    const int lq = ln >> 4, lr = ln & 15;
    int mt, nt; tile_remap(mt, nt);
    const int m0 = mt * 128, n0 = nt * 128;

    const int kcs = ((t & 3) ^ ((t >> 3) & 3)) * 8;
    const u16* Ab = A + (size_t)(m0 + (t >> 2)) * K + kcs;
    const u16* Gb = Wg + (size_t)(n0 + (t >> 2)) * K + kcs;
    const u16* Ub = Wu + (size_t)(n0 + (t >> 2)) * K + kcs;
    u16* sAd = sA + t * 8;
    u16* sGd = sG + t * 8;
    u16* sUd = sU + t * 8;
    const size_t half = (size_t)64 * K;
    const int sw = (lr >> 1) & 3;

    f32x4 ag[4][4] = {}, au[4][4] = {};

    for (int k0 = 0; k0 < K; k0 += 32) {
        __syncthreads();
        gld16(Ab + k0, sAd);
        gld16(Ab + half + k0, sAd + 2048);
        gld16(Gb + k0, sGd);
        gld16(Gb + half + k0, sGd + 2048);
        gld16(Ub + k0, sUd);
        gld16(Ub + half + k0, sUd + 2048);
        __syncthreads();
        s16x8 af[4], bg[4], bu[4];
#pragma unroll
        for (int i = 0; i < 4; i++)
            af[i] = *(const s16x8*)&sA[(wr * 64 + i * 16 + lr) * 32 + (lq ^ sw) * 8];
#pragma unroll
        for (int j = 0; j < 4; j++) {
            bg[j] = *(const s16x8*)&sG[(wc * 64 + j * 16 + lr) * 32 + (lq ^ sw) * 8];
            bu[j] = *(const s16x8*)&sU[(wc * 64 + j * 16 + lr) * 32 + (lq ^ sw) * 8];
        }
#pragma unroll
        for (int i = 0; i < 4; i++)
#pragma unroll
            for (int j = 0; j < 4; j++) {
                ag[i][j] = __builtin_amdgcn_mfma_f32_16x16x32_bf16(af[i], bg[j], ag[i][j], 0, 0, 0);
                au[i][j] = __builtin_amdgcn_mfma_f32_16x16x32_bf16(af[i], bu[j], au[i][j], 0, 0, 0);
            }
    }

#pragma unroll
    for (int i = 0; i < 4; i++)
#pragma unroll
        for (int j = 0; j < 4; j++)
#pragma unroll
            for (int r = 0; r < 4; r++) {
                const int m = m0 + wr * 64 + i * 16 + lq * 4 + r;
                const int n = n0 + wc * 64 + j * 16 + lr;
                const float gv = ag[i][j][r];
                const float sg = gv / (1.f + __expf(-gv));
                G[(size_t)m * N + n] = f2b(sg * au[i][j][r]);
            }
}

// ---------------------------------------------------------------------------
// Fused QKV projection. A[M,2048]; n-tiles 0..15 -> Q[M,2048],
// 16..19 -> K[M,512], 20..23 -> V^T scatter [B,NKV,HD,S]. K=2048.
// ---------------------------------------------------------------------------
__global__ __launch_bounds__(256)
void gemm_qkv(const u16* __restrict__ A, const u16* __restrict__ wq,
              const u16* __restrict__ wk, const u16* __restrict__ wv,
              u16* __restrict__ Q, u16* __restrict__ Kk, u16* __restrict__ VT)
{
    __shared__ u16 sA[128 * 32];
    __shared__ u16 sB[128 * 32];
    const int t = threadIdx.x;
    const int w = t >> 6, ln = t & 63;
    const int wr = w >> 1, wc = w & 1;
    const int lq = ln >> 4, lr = ln & 15;
    int mt, nt; tile_remap(mt, nt);
    const int m0 = mt * 128;
    const int K = 2048;

    const u16* Wbase; int nl, route;
    if (nt < 16)      { Wbase = wq; nl = nt * 128;        route = 0; }
    else if (nt < 20) { Wbase = wk; nl = (nt - 16) * 128; route = 1; }
    else              { Wbase = wv; nl = (nt - 20) * 128; route = 2; }

    const int kcs = ((t & 3) ^ ((t >> 3) & 3)) * 8;
    const u16* Ab = A + (size_t)(m0 + (t >> 2)) * K + kcs;
    const u16* Bb = Wbase + (size_t)(nl + (t >> 2)) * K + kcs;
    u16* sAd = sA + t * 8;
    u16* sBd = sB + t * 8;
    const size_t half = (size_t)64 * K;
    const int sw = (lr >> 1) & 3;

    f32x4 acc[4][4] = {};

    for (int k0 = 0; k0 < K; k0 += 32) {
        __syncthreads();
        gld16(Ab + k0, sAd);
        gld16(Ab + half + k0, sAd + 2048);
        gld16(Bb + k0, sBd);
        gld16(Bb + half + k0, sBd + 2048);
        __syncthreads();
        s16x8 af[4], bf[4];
#pragma unroll
        for (int i = 0; i < 4; i++)
            af[i] = *(const s16x8*)&sA[(wr * 64 + i * 16 + lr) * 32 + (lq ^ sw) * 8];
#pragma unroll
        for (int j = 0; j < 4; j++)
            bf[j] = *(const s16x8*)&sB[(wc * 64 + j * 16 + lr) * 32 + (lq ^ sw) * 8];
#pragma unroll
        for (int i = 0; i < 4; i++)
#pragma unroll
            for (int j = 0; j < 4; j++)
                acc[i][j] = __builtin_amdgcn_mfma_f32_16x16x32_bf16(af[i], bf[j], acc[i][j], 0, 0, 0);
    }

#pragma unroll
    for (int i = 0; i < 4; i++)
#pragma unroll
        for (int j = 0; j < 4; j++)
#pragma unroll
            for (int r = 0; r < 4; r++) {
                const int m = m0 + wr * 64 + i * 16 + lq * 4 + r;
                const int nc = nl + wc * 64 + j * 16 + lr;   // col within route
                const u16 v = f2b(acc[i][j][r]);
                if (route == 0) {
                    Q[(size_t)m * 2048 + nc] = v;
                } else if (route == 1) {
                    Kk[(size_t)m * 512 + nc] = v;
                } else {
                    const int bb = m >> 11, s = m & 2047;
                    const int kv = nc >> 7, d = nc & 127;
                    VT[(((size_t)bb * 4 + kv) * 128 + d) * 2048 + s] = v;
                }
            }
}

// RMSNorm over rows of 2048, fp32 input, bf16 weight/output.
__global__ __launch_bounds__(256)
void rmsnorm_k(const float* __restrict__ x, const u16* __restrict__ wt, u16* __restrict__ o)
{
    __shared__ float red[4];
    const int row = blockIdx.x, t = threadIdx.x;
    const float* xr = x + (size_t)row * 2048;
    float4 a = *(const float4*)(xr + t * 8);
    float4 b = *(const float4*)(xr + t * 8 + 4);
    float xf[8] = {a.x, a.y, a.z, a.w, b.x, b.y, b.z, b.w};
    float ss = 0.f;
#pragma unroll
    for (int i = 0; i < 8; i++) ss += xf[i] * xf[i];
#pragma unroll
    for (int off = 1; off < 64; off <<= 1) ss += __shfl_xor(ss, off);
    if ((t & 63) == 0) red[t >> 6] = ss;
    __syncthreads();
    const float tot = red[0] + red[1] + red[2] + red[3];
    const float sc = rsqrtf(tot * (1.f / 2048.f) + 1e-5f);
    s16x8 wv = *(const s16x8*)(wt + t * 8);
    s16x8 ov;
#pragma unroll
    for (int i = 0; i < 8; i++) ov[i] = (short)f2b(xf[i] * sc * b2f((u16)wv[i]));
    *(s16x8*)(o + (size_t)row * 2048 + t * 8) = ov;
}

// ---------------------------------------------------------------------------
// Flash attention, causal. Q:[B,S,2048] K:[B,S,512] VT:[B,NKV,128,S].
// 128 q-rows/block, 4 waves x 32 rows, 64-key tiles, XOR-swizzled LDS
// (conflict-free, verified round 4).
// ---------------------------------------------------------------------------
__global__ __launch_bounds__(256)
void attn_k(const u16* __restrict__ Q, const u16* __restrict__ K,
            const u16* __restrict__ VT, u16* __restrict__ O)
{
    __shared__ u16 kbuf[64 * 128];
    __shared__ u16 vtbuf[128 * 64];
    __shared__ u16 pbuf[4 * 32 * 64];
    const int qt = blockIdx.x, bh = blockIdx.y;
    const int b = bh >> 4, h = bh & 15, kv = h >> 2;
    const int t = threadIdx.x, w = t >> 6, ln = t & 63;
    const int lq = ln >> 4, lr = ln & 15;
    const u16* qp = Q + (size_t)b * 2048 * 2048 + h * 128;
    const u16* kp = K + (size_t)b * 2048 * 512 + kv * 128;
    const u16* vp = VT + ((size_t)b * 4 + kv) * 128 * 2048;
    const int wrow = qt * 128 + w * 32;

    s16x8 qf[2][4];
#pragma unroll
    for (int i = 0; i < 2; i++)
#pragma unroll
        for (int ks = 0; ks < 4; ks++)
            qf[i][ks] = *(const s16x8*)(qp + (size_t)(wrow + i * 16 + lr) * 2048 + ks * 32 + lq * 8);

    f32x4 oacc[2][8] = {};
    float mi[2][4], li[2][4];
#pragma unroll
    for (int i = 0; i < 2; i++)
#pragma unroll
        for (int r = 0; r < 4; r++) { mi[i][r] = -INFINITY; li[i][r] = 0.f; }

    const int nkt = 2 * qt + 2;
    const int kswz = (t & 15) ^ ((t >> 4) & 15);
    const int vswz = (t & 7) ^ ((t >> 3) & 7);
    const u16* kg0 = kp + (size_t)(t >> 4) * 512 + kswz * 8;
    const u16* vg0 = vp + (size_t)(t >> 3) * 2048 + vswz * 8;
    u16* kd = kbuf + t * 8;
    u16* vd = vtbuf + t * 8;
    u16* pw = pbuf + w * 2048;
    const int lr7 = lr & 7;

    for (int kt = 0; kt < nkt; ++kt) {
        __syncthreads();
        const u16* kg = kg0 + (size_t)kt * 64 * 512;
#pragma unroll
        for (int i = 0; i < 4; i++) gld16(kg + (size_t)i * 16 * 512, kd + i * 2048);
        const u16* vg = vg0 + kt * 64;
#pragma unroll
        for (int i = 0; i < 4; i++) gld16(vg + (size_t)i * 32 * 2048, vd + i * 2048);
        __syncthreads();

        f32x4 sacc[2][4] = {};
#pragma unroll
        for (int ks = 0; ks < 4; ks++) {
            s16x8 kf[4];
#pragma unroll
            for (int j = 0; j < 4; j++)
                kf[j] = *(const s16x8*)&kbuf[(j * 16 + lr) * 128 + ((ks * 4 + lq) ^ lr) * 8];
#pragma unroll
            for (int i = 0; i < 2; i++)
#pragma unroll
                for (int j = 0; j < 4; j++)
                    sacc[i][j] = __builtin_amdgcn_mfma_f32_16x16x32_bf16(qf[i][ks], kf[j], sacc[i][j], 0, 0, 0);
        }

        const float scale = 0.08838834764831845f;  // 1/sqrt(128)
        const bool domask = (kt >= 2 * qt);
#pragma unroll
        for (int i = 0; i < 2; i++)
#pragma unroll
            for (int j = 0; j < 4; j++)
#pragma unroll
                for (int r = 0; r < 4; r++) {
                    float s = sacc[i][j][r] * scale;
                    if (domask) {
                        const int key = kt * 64 + j * 16 + lr;
                        const int row = wrow + i * 16 + lq * 4 + r;
                        if (key > row) s = -1e30f;
                    }
                    sacc[i][j][r] = s;
                }
        float alpha[2][4];
#pragma unroll
        for (int i = 0; i < 2; i++)
#pragma unroll
            for (int r = 0; r < 4; r++) {
                float tm = fmaxf(fmaxf(sacc[i][0][r], sacc[i][1][r]),
                                 fmaxf(sacc[i][2][r], sacc[i][3][r]));
#pragma unroll
                for (int off = 1; off < 16; off <<= 1) tm = fmaxf(tm, __shfl_xor(tm, off));
                const float mn = fmaxf(mi[i][r], tm);
                alpha[i][r] = exp2f((mi[i][r] - mn) * LOG2E);
                mi[i][r] = mn;
            }
#pragma unroll
        for (int i = 0; i < 2; i++)
#pragma unroll
            for (int r = 0; r < 4; r++) {
                const int qrow = i * 16 + lq * 4 + r;
                float rs = 0.f;
#pragma unroll
                for (int j = 0; j < 4; j++) {
                    const float p = exp2f((sacc[i][j][r] - mi[i][r]) * LOG2E);
                    rs += p;
                    const int key = j * 16 + lr;
                    pw[qrow * 64 + (((key >> 3) ^ (qrow & 7)) << 3) + (key & 7)] = f2b(p);
                }
#pragma unroll
                for (int off = 1; off < 16; off <<= 1) rs += __shfl_xor(rs, off);
                li[i][r] = li[i][r] * alpha[i][r] + rs;
            }
#pragma unroll
        for (int i = 0; i < 2; i++)
#pragma unroll
            for (int jo = 0; jo < 8; jo++)
#pragma unroll
                for (int r = 0; r < 4; r++) oacc[i][jo][r] *= alpha[i][r];
        __syncthreads();  // pbuf writes drained before A-frag reads
#pragma unroll
        for (int ks2 = 0; ks2 < 2; ks2++) {
            s16x8 pf[2];
#pragma unroll
            for (int i = 0; i < 2; i++)
                pf[i] = *(const s16x8*)&pw[(i * 16 + lr) * 64 + ((ks2 * 4 + lq) ^ lr7) * 8];
#pragma unroll
            for (int jo = 0; jo < 8; jo++) {
                s16x8 vf = *(const s16x8*)&vtbuf[(jo * 16 + lr) * 64 + ((ks2 * 4 + lq) ^ lr7) * 8];
#pragma unroll
                for (int i = 0; i < 2; i++)
                    oacc[i][jo] = __builtin_amdgcn_mfma_f32_16x16x32_bf16(pf[i], vf, oacc[i][jo], 0, 0, 0);
            }
        }
    }

#pragma unroll
    for (int i = 0; i < 2; i++)
#pragma unroll
        for (int jo = 0; jo < 8; jo++)
#pragma unroll
            for (int r = 0; r < 4; r++) {
                const int row = wrow + i * 16 + lq * 4 + r;
                const int d = jo * 16 + lr;
                const float v = oacc[i][jo][r] / li[i][r];
                O[((size_t)b * 2048 + row) * 2048 + h * 128 + d] = f2b(v);
            }
}

extern "C" void kernel_launch(void* const* d_in, const int* in_sizes, int n_in,
                              void* d_out, int out_size, void* d_ws, size_t ws_size,
                              hipStream_t stream)
{
    (void)in_sizes; (void)n_in; (void)out_size; (void)ws_size;
    const float* x = (const float*)d_in[0];   // fp32 inputs
    float* out = (float*)d_out;               // fp32 output
    u16* ws = (u16*)d_ws;

    // ---- workspace layout (u16 elements); weight region contiguous for cvt_all ----
    u16* wqb = ws;                  //  4,194,304
    u16* wkb = ws + 4194304;        //  1,048,576
    u16* wvb = ws + 5242880;        //  1,048,576
    u16* wob = ws + 6291456;        //  4,194,304
    u16* wgb = ws + 10485760;       // 16,777,216
    u16* wub = ws + 27262976;       // 16,777,216
    u16* wdb = ws + 44040192;       // 16,777,216
    u16* n1b = ws + 60817408;       //      2,048
    u16* n2b = ws + 60819456;       //      2,048
    u16* h1  = ws + 60821504;       //  8,388,608  norm1 out, later attn out
    u16* q   = ws + 69210112;       //  8,388,608  Q, later norm2 out
    u16* kk  = ws + 77598720;       //  2,097,152  K  [B,S,512]
    u16* vT  = ws + 79695872;       //  2,097,152  V^T [B,NKV,HD,S]
    u16* g   = ws + 81793024;       // 33,554,432  silu(gate)*up

    // ---- all weights fp32 -> bf16 in ONE launch ----
    cvt_all<<<29698, 256, 0, stream>>>(
        (const float*)d_in[2], (const float*)d_in[3], (const float*)d_in[4],
        (const float*)d_in[5], (const float*)d_in[8], (const float*)d_in[9],
        (const float*)d_in[10], (const float*)d_in[6], (const float*)d_in[7], wqb);
    // d_in[1] = attention_mask: causal, analytic.

    // ---- transformer block (residual stream in fp32) ----
    rmsnorm_k<<<4096, 256, 0, stream>>>(x, n1b, h1);
    gemm_qkv<<<dim3(24, 32), 256, 0, stream>>>(h1, wqb, wkb, wvb, q, kk, vT);
    attn_k<<<dim3(16, 32), 256, 0, stream>>>(q, kk, vT, h1);
    gemm_addf<<<dim3(16, 32), 256, 0, stream>>>(h1, wob, out, x, 2048, 2048);   // r1 = x + attn@wo^T
    rmsnorm_k<<<4096, 256, 0, stream>>>(out, n2b, q);
    gemm_gu<<<dim3(64, 32), 256, 0, stream>>>(q, wgb, wub, g, 8192, 2048);      // g = silu(x@wg^T)*(x@wu^T)
    gemm_addf<<<dim3(16, 32), 256, 0, stream>>>(g, wdb, out, out, 2048, 8192);  // out = r1 + g@wd^T
}